// Round 1
// baseline (159.216 us; speedup 1.0000x reference)
//
#include <hip/hip_runtime.h>

// DirectionalScan: B=4, H=64, W=64, D=512, N=8
// out = ((scan_h(x) + scan_v(x)) @ Wp^T) + b_proj
#define BB 4
#define HH 64
#define WW 64
#define DD 512
#define NS 8
#define MROWS (BB * HH * WW)   // 16384

// ---------------- scan kernels ----------------
// One thread per (sequence, channel d). 8 diagonal states per thread.
// HORIZ=true : sequences are (b, w), scan over h (stride W*D). Writes y.
// HORIZ=false: sequences are (b, h), scan over w (stride D).   Accumulates y.
template <bool HORIZ>
__global__ __launch_bounds__(256) void scan_kernel(
    const float* __restrict__ x, const float* __restrict__ A,
    const float* __restrict__ Bm, const float* __restrict__ Cm,
    const float* __restrict__ Dsk, float* __restrict__ y) {
  const int seq = blockIdx.x;                  // 0..255  (b*64 + r)
  const int d = blockIdx.y * 256 + threadIdx.x;
  const int b = seq >> 6;
  const int r = seq & 63;

  size_t base, step;
  if (HORIZ) {  // r = w, scan over h
    base = ((size_t)b * HH * WW + r) * DD + d;
    step = (size_t)WW * DD;
  } else {      // r = h, scan over w
    base = ((size_t)(b * HH + r)) * WW * DD + d;
    step = DD;
  }

  float a[NS], bm[NS], cm[NS], s[NS];
#pragma unroll
  for (int i = 0; i < NS; i += 4) {
    float4 t;
    t = *(const float4*)&A[(size_t)d * NS + i];
    a[i] = t.x; a[i + 1] = t.y; a[i + 2] = t.z; a[i + 3] = t.w;
    t = *(const float4*)&Bm[(size_t)d * NS + i];
    bm[i] = t.x; bm[i + 1] = t.y; bm[i + 2] = t.z; bm[i + 3] = t.w;
    t = *(const float4*)&Cm[(size_t)d * NS + i];
    cm[i] = t.x; cm[i + 1] = t.y; cm[i + 2] = t.z; cm[i + 3] = t.w;
  }
  const float dk = Dsk[d];
#pragma unroll
  for (int i = 0; i < NS; ++i) s[i] = 0.f;

  // 8 chunks of 8 steps: batch the 8 loads up front so HBM latency is
  // paid once per chunk, not once per step.
  for (int c = 0; c < 8; ++c) {
    float xs[8];
#pragma unroll
    for (int i = 0; i < 8; ++i) xs[i] = x[base + (size_t)i * step];
#pragma unroll
    for (int i = 0; i < 8; ++i) {
      const float xv = xs[i];
      float acc = dk * xv;
#pragma unroll
      for (int n = 0; n < NS; ++n) {
        s[n] = fmaf(a[n], s[n], bm[n] * xv);
        acc = fmaf(s[n], cm[n], acc);
      }
      const size_t idx = base + (size_t)i * step;
      if (HORIZ) y[idx] = acc;
      else       y[idx] += acc;
    }
    base += 8 * step;
  }
}

// ---------------- f32 tiled GEMM: out[m][j] = sum_k Y[m][k]*Wp[j][k] + b[j] --
#define BM 64
#define BN 64
#define BK 16

__global__ __launch_bounds__(256) void gemm_kernel(
    const float* __restrict__ Yv, const float* __restrict__ Wp,
    const float* __restrict__ bias, float* __restrict__ out) {
  __shared__ float As[BK][BM + 4];  // +4 keeps float4 alignment, breaks pow2 stride
  __shared__ float Bs[BK][BN + 4];

  const int tid = threadIdx.x;
  const int tx = tid & 15;   // n-dir micro-tile
  const int ty = tid >> 4;   // m-dir micro-tile
  const int m0 = blockIdx.y * BM;
  const int n0 = blockIdx.x * BN;

  const int lrow = tid >> 2;        // 0..63 : tile row to load
  const int lk4 = (tid & 3) * 4;    // 0,4,8,12 : k-segment

  float acc[4][4] = {};

  for (int k0 = 0; k0 < DD; k0 += BK) {
    const float4 av = *(const float4*)&Yv[(size_t)(m0 + lrow) * DD + k0 + lk4];
    const float4 bv = *(const float4*)&Wp[(size_t)(n0 + lrow) * DD + k0 + lk4];
    __syncthreads();  // previous iteration's LDS reads done
    As[lk4 + 0][lrow] = av.x; As[lk4 + 1][lrow] = av.y;
    As[lk4 + 2][lrow] = av.z; As[lk4 + 3][lrow] = av.w;
    Bs[lk4 + 0][lrow] = bv.x; Bs[lk4 + 1][lrow] = bv.y;
    Bs[lk4 + 2][lrow] = bv.z; Bs[lk4 + 3][lrow] = bv.w;
    __syncthreads();
#pragma unroll
    for (int kk = 0; kk < BK; ++kk) {
      const float4 a4 = *(const float4*)&As[kk][ty * 4];
      const float4 b4 = *(const float4*)&Bs[kk][tx * 4];
      const float am[4] = {a4.x, a4.y, a4.z, a4.w};
      const float bn[4] = {b4.x, b4.y, b4.z, b4.w};
#pragma unroll
      for (int i = 0; i < 4; ++i)
#pragma unroll
        for (int j = 0; j < 4; ++j) acc[i][j] = fmaf(am[i], bn[j], acc[i][j]);
    }
  }

  const float4 bb = *(const float4*)&bias[n0 + tx * 4];
#pragma unroll
  for (int i = 0; i < 4; ++i) {
    float4 o;
    o.x = acc[i][0] + bb.x;
    o.y = acc[i][1] + bb.y;
    o.z = acc[i][2] + bb.z;
    o.w = acc[i][3] + bb.w;
    *(float4*)&out[(size_t)(m0 + ty * 4 + i) * DD + n0 + tx * 4] = o;
  }
}

// ---------------- launcher ----------------
extern "C" void kernel_launch(void* const* d_in, const int* in_sizes, int n_in,
                              void* d_out, int out_size, void* d_ws,
                              size_t ws_size, hipStream_t stream) {
  // setup_inputs order: x, h, w, A, Bm, Cm, D_skip, Wp, b_proj
  const float* x = (const float*)d_in[0];
  const float* A = (const float*)d_in[3];
  const float* Bm = (const float*)d_in[4];
  const float* Cm = (const float*)d_in[5];
  const float* Dsk = (const float*)d_in[6];
  const float* Wp = (const float*)d_in[7];
  const float* bpj = (const float*)d_in[8];
  float* out = (float*)d_out;
  float* yws = (float*)d_ws;  // needs MROWS*DD*4 = 32 MB

  const dim3 scan_grid(BB * 64, DD / 256);  // 256 sequences x 2 channel-blocks
  scan_kernel<true><<<scan_grid, 256, 0, stream>>>(x, A, Bm, Cm, Dsk, yws);
  scan_kernel<false><<<scan_grid, 256, 0, stream>>>(x, A, Bm, Cm, Dsk, yws);

  const dim3 gemm_grid(DD / BN, MROWS / BM);  // (8, 256)
  gemm_kernel<<<gemm_grid, 256, 0, stream>>>(yws, Wp, bpj, out);
}

// Round 2
// 54.693 us; speedup vs baseline: 2.9111x; 2.9111x over previous
//
#include <hip/hip_runtime.h>

// DirectionalScan: B=4, H=64, W=64, D=512, N=8
// out = ((scan_h(x) + scan_v(x)) @ Wp^T) + b_proj
#define BB 4
#define HH 64
#define WW 64
#define DD 512
#define NS 8
#define MROWS (BB * HH * WW)  // 16384

typedef __attribute__((ext_vector_type(8))) __bf16 bf16x8;
typedef __attribute__((ext_vector_type(4))) float f32x4;

__device__ inline short f2bf(float f) {  // RNE f32 -> bf16 bits
  unsigned u = __float_as_uint(f);
  return (short)((u + 0x7fff + ((u >> 16) & 1)) >> 16);
}
__device__ inline float bf2f(short s) {
  return __uint_as_float(((unsigned)(unsigned short)s) << 16);
}

// ---------------- scan kernels (y stored as bf16) ----------------
template <bool HORIZ>
__global__ __launch_bounds__(256) void scan_kernel(
    const float* __restrict__ x, const float* __restrict__ A,
    const float* __restrict__ Bm, const float* __restrict__ Cm,
    const float* __restrict__ Dsk, short* __restrict__ y) {
  const int seq = blockIdx.x;  // 0..255
  const int d = blockIdx.y * 256 + threadIdx.x;
  const int b = seq >> 6;
  const int r = seq & 63;

  size_t base, step;
  if (HORIZ) {
    base = ((size_t)b * HH * WW + r) * DD + d;
    step = (size_t)WW * DD;
  } else {
    base = ((size_t)(b * HH + r)) * WW * DD + d;
    step = DD;
  }

  float a[NS], bm[NS], cm[NS], s[NS];
#pragma unroll
  for (int i = 0; i < NS; i += 4) {
    float4 t;
    t = *(const float4*)&A[(size_t)d * NS + i];
    a[i] = t.x; a[i + 1] = t.y; a[i + 2] = t.z; a[i + 3] = t.w;
    t = *(const float4*)&Bm[(size_t)d * NS + i];
    bm[i] = t.x; bm[i + 1] = t.y; bm[i + 2] = t.z; bm[i + 3] = t.w;
    t = *(const float4*)&Cm[(size_t)d * NS + i];
    cm[i] = t.x; cm[i + 1] = t.y; cm[i + 2] = t.z; cm[i + 3] = t.w;
  }
  const float dk = Dsk[d];
#pragma unroll
  for (int i = 0; i < NS; ++i) s[i] = 0.f;

  for (int c = 0; c < 8; ++c) {
    float xs[8];
#pragma unroll
    for (int i = 0; i < 8; ++i) xs[i] = x[base + (size_t)i * step];
#pragma unroll
    for (int i = 0; i < 8; ++i) {
      const float xv = xs[i];
      float acc = dk * xv;
#pragma unroll
      for (int n = 0; n < NS; ++n) {
        s[n] = fmaf(a[n], s[n], bm[n] * xv);
        acc = fmaf(s[n], cm[n], acc);
      }
      const size_t idx = base + (size_t)i * step;
      if (HORIZ) y[idx] = f2bf(acc);
      else       y[idx] = f2bf(bf2f(y[idx]) + acc);
    }
    base += 8 * step;
  }
}

// ---------------- Wp f32 -> bf16 ----------------
__global__ __launch_bounds__(256) void conv_bf16(const float* __restrict__ in,
                                                 short* __restrict__ o) {
  const int i = (blockIdx.x * 256 + threadIdx.x) * 8;
  const float4 v0 = *(const float4*)&in[i];
  const float4 v1 = *(const float4*)&in[i + 4];
  short r[8];
  r[0] = f2bf(v0.x); r[1] = f2bf(v0.y); r[2] = f2bf(v0.z); r[3] = f2bf(v0.w);
  r[4] = f2bf(v1.x); r[5] = f2bf(v1.y); r[6] = f2bf(v1.z); r[7] = f2bf(v1.w);
  *(short4*)&o[i] = *(short4*)&r[0];
  *(short4*)&o[i + 4] = *(short4*)&r[4];
}

// ---------------- bf16 MFMA GEMM: out = Y @ Wp^T + b ----------------
// m97 structure: 128x128 tile, BK=64, 4 waves (2x2), global_load_lds w16.
#define GBM 128
#define GBN 128
#define GBK 64

__global__ __launch_bounds__(256) void gemm_bf16(
    const short* __restrict__ Y, const short* __restrict__ Wb,
    const float* __restrict__ bias, float* __restrict__ out) {
  __shared__ __align__(16) short As[GBM * GBK];  // [128][64] row-major, 16 KB
  __shared__ __align__(16) short Bs[GBN * GBK];

  const int tid = threadIdx.x;
  const int lane = tid & 63;
  const int wid = tid >> 6;           // 0..3
  const int wm = wid >> 1, wn = wid & 1;
  const int m0 = blockIdx.y * GBM;
  const int n0 = blockIdx.x * GBN;

  const int srow = lane >> 3;         // 0..7 row within 8-row chunk
  const int scol = (lane & 7) * 8;    // elem col within row

  f32x4 acc[4][4];
#pragma unroll
  for (int m = 0; m < 4; ++m)
#pragma unroll
    for (int n = 0; n < 4; ++n) acc[m][n] = (f32x4){0.f, 0.f, 0.f, 0.f};

  auto stage = [&](int k0) {
#pragma unroll
    for (int c = 0; c < 4; ++c) {
      const int chunk = wid * 4 + c;          // 0..15 (8 rows each)
      const int row = chunk * 8 + srow;
      const short* ga = &Y[(size_t)(m0 + row) * DD + k0 + scol];
      const short* gb = &Wb[(size_t)(n0 + row) * DD + k0 + scol];
      __builtin_amdgcn_global_load_lds(
          (const __attribute__((address_space(1))) unsigned int*)ga,
          (__attribute__((address_space(3))) unsigned int*)((char*)As + chunk * 1024),
          16, 0, 0);
      __builtin_amdgcn_global_load_lds(
          (const __attribute__((address_space(1))) unsigned int*)gb,
          (__attribute__((address_space(3))) unsigned int*)((char*)Bs + chunk * 1024),
          16, 0, 0);
    }
  };

  const int arow = wm * 64 + (lane & 15);
  const int brow = wn * 64 + (lane & 15);
  const int kfr = (lane >> 4) * 8;

  stage(0);
  const int NK = DD / GBK;  // 8
  for (int k = 0; k < NK; ++k) {
    __syncthreads();  // staging drained (vmcnt0 before barrier), prior compute done
#pragma unroll
    for (int kk = 0; kk < GBK; kk += 32) {
      bf16x8 af[4], bfr[4];
      const int kcol = kk + kfr;
#pragma unroll
      for (int m = 0; m < 4; ++m)
        af[m] = *(const bf16x8*)(const void*)&As[(arow + m * 16) * GBK + kcol];
#pragma unroll
      for (int n = 0; n < 4; ++n)
        bfr[n] = *(const bf16x8*)(const void*)&Bs[(brow + n * 16) * GBK + kcol];
#pragma unroll
      for (int m = 0; m < 4; ++m)
#pragma unroll
        for (int n = 0; n < 4; ++n)
          acc[m][n] = __builtin_amdgcn_mfma_f32_16x16x32_bf16(
              af[m], bfr[n], acc[m][n], 0, 0, 0);
    }
    if (k + 1 < NK) {
      __syncthreads();  // all waves done reading LDS
      stage((k + 1) * GBK);
    }
  }

  // epilogue: D layout col=lane&15, row=(lane>>4)*4+j  [m89 verified]
  const int c16 = lane & 15;
  const int r4 = (lane >> 4) * 4;
#pragma unroll
  for (int m = 0; m < 4; ++m) {
    const int rowb = m0 + wm * 64 + m * 16 + r4;
#pragma unroll
    for (int n = 0; n < 4; ++n) {
      const int col = n0 + wn * 64 + n * 16 + c16;
      const float bv = bias[col];
#pragma unroll
      for (int j = 0; j < 4; ++j)
        out[(size_t)(rowb + j) * DD + col] = acc[m][n][j] + bv;
    }
  }
}

// ---------------- launcher ----------------
extern "C" void kernel_launch(void* const* d_in, const int* in_sizes, int n_in,
                              void* d_out, int out_size, void* d_ws,
                              size_t ws_size, hipStream_t stream) {
  const float* x = (const float*)d_in[0];
  const float* A = (const float*)d_in[3];
  const float* Bm = (const float*)d_in[4];
  const float* Cm = (const float*)d_in[5];
  const float* Dsk = (const float*)d_in[6];
  const float* Wp = (const float*)d_in[7];
  const float* bpj = (const float*)d_in[8];
  float* out = (float*)d_out;

  short* yws = (short*)d_ws;                                  // 16 MB bf16 y
  short* wb = (short*)((char*)d_ws + (size_t)MROWS * DD * 2);  // 512 KB bf16 Wp

  conv_bf16<<<DD * DD / (256 * 8), 256, 0, stream>>>(Wp, wb);

  const dim3 scan_grid(BB * 64, DD / 256);
  scan_kernel<true><<<scan_grid, 256, 0, stream>>>(x, A, Bm, Cm, Dsk, yws);
  scan_kernel<false><<<scan_grid, 256, 0, stream>>>(x, A, Bm, Cm, Dsk, yws);

  const dim3 gemm_grid(DD / GBN, MROWS / GBM);  // (4, 128)
  gemm_bf16<<<gemm_grid, 256, 0, stream>>>(yws, wb, bpj, out);
}

// Round 3
// 48.208 us; speedup vs baseline: 3.3027x; 1.1345x over previous
//
#include <hip/hip_runtime.h>

// DirectionalScan: B=4, H=64, W=64, D=512, N=8
// out = ((scan_h(x) + scan_v(x)) @ Wp^T) + b_proj
#define BB 4
#define HH 64
#define WW 64
#define DD 512
#define NS 8
#define MROWS (BB * HH * WW)  // 16384

typedef __attribute__((ext_vector_type(8))) __bf16 bf16x8;
typedef __attribute__((ext_vector_type(4))) float f32x4;

__device__ inline short f2bf(float f) {  // RNE f32 -> bf16 bits
  unsigned u = __float_as_uint(f);
  return (short)((u + 0x7fff + ((u >> 16) & 1)) >> 16);
}
__device__ inline float bf2f(short s) {
  return __uint_as_float(((unsigned)(unsigned short)s) << 16);
}

// ---------------- scan kernels (y stored as bf16) ----------------
// HORIZ=true : sequences (b,w), scan over h (stride W*D). Writes y.
//              blocks with blockIdx.x >= 256 instead convert Wp -> bf16.
// HORIZ=false: sequences (b,h), scan over w (stride D). y += (RMW, batched).
template <bool HORIZ>
__global__ __launch_bounds__(256) void scan_kernel(
    const float* __restrict__ x, const float* __restrict__ A,
    const float* __restrict__ Bm, const float* __restrict__ Cm,
    const float* __restrict__ Dsk, short* __restrict__ y,
    const float* __restrict__ Wp, short* __restrict__ wb) {
  if (HORIZ && blockIdx.x >= 256) {
    // fused Wp f32->bf16 conversion: 128 conv blocks x 256 thr x 8 elems
    const int cid = (blockIdx.x - 256) * 2 + blockIdx.y;  // 0..127
    const int i = (cid * 256 + (int)threadIdx.x) * 8;
    const float4 v0 = *(const float4*)&Wp[i];
    const float4 v1 = *(const float4*)&Wp[i + 4];
    short r[8];
    r[0] = f2bf(v0.x); r[1] = f2bf(v0.y); r[2] = f2bf(v0.z); r[3] = f2bf(v0.w);
    r[4] = f2bf(v1.x); r[5] = f2bf(v1.y); r[6] = f2bf(v1.z); r[7] = f2bf(v1.w);
    *(short4*)&wb[i] = *(short4*)&r[0];
    *(short4*)&wb[i + 4] = *(short4*)&r[4];
    return;
  }

  const int seq = blockIdx.x;  // 0..255
  const int d = blockIdx.y * 256 + threadIdx.x;
  const int b = seq >> 6;
  const int r = seq & 63;

  size_t base, step;
  if (HORIZ) {
    base = ((size_t)b * HH * WW + r) * DD + d;
    step = (size_t)WW * DD;
  } else {
    base = ((size_t)(b * HH + r)) * WW * DD + d;
    step = DD;
  }

  float a[NS], bm[NS], cm[NS], s[NS];
#pragma unroll
  for (int i = 0; i < NS; i += 4) {
    float4 t;
    t = *(const float4*)&A[(size_t)d * NS + i];
    a[i] = t.x; a[i + 1] = t.y; a[i + 2] = t.z; a[i + 3] = t.w;
    t = *(const float4*)&Bm[(size_t)d * NS + i];
    bm[i] = t.x; bm[i + 1] = t.y; bm[i + 2] = t.z; bm[i + 3] = t.w;
    t = *(const float4*)&Cm[(size_t)d * NS + i];
    cm[i] = t.x; cm[i + 1] = t.y; cm[i + 2] = t.z; cm[i + 3] = t.w;
  }
  const float dk = Dsk[d];
#pragma unroll
  for (int i = 0; i < NS; ++i) s[i] = 0.f;

  // Double-buffered 8-step chunks: chunk c+1's x (and y for RMW) loads are
  // issued before chunk c's compute, so latency hides under the FMA chain.
  float xs[2][8];
  float yp[2][8];
#pragma unroll
  for (int i = 0; i < 8; ++i) xs[0][i] = x[base + (size_t)i * step];
  if (!HORIZ) {
#pragma unroll
    for (int i = 0; i < 8; ++i) yp[0][i] = bf2f(y[base + (size_t)i * step]);
  }

#pragma unroll 2  // keeps cur/nxt compile-time (no scratch), limits hoisting
  for (int c = 0; c < 8; ++c) {
    const int cur = c & 1, nxt = cur ^ 1;
    const size_t nbase = base + 8 * step;
    if (c < 7) {
#pragma unroll
      for (int i = 0; i < 8; ++i) xs[nxt][i] = x[nbase + (size_t)i * step];
      if (!HORIZ) {
#pragma unroll
        for (int i = 0; i < 8; ++i)
          yp[nxt][i] = bf2f(y[nbase + (size_t)i * step]);
      }
    }
#pragma unroll
    for (int i = 0; i < 8; ++i) {
      const float xv = xs[cur][i];
      float acc = dk * xv;
#pragma unroll
      for (int n = 0; n < NS; ++n) {
        s[n] = fmaf(a[n], s[n], bm[n] * xv);
        acc = fmaf(s[n], cm[n], acc);
      }
      if (!HORIZ) acc += yp[cur][i];
      y[base + (size_t)i * step] = f2bf(acc);
    }
    base = nbase;
  }
}

// ---------------- bf16 MFMA GEMM: out = Y @ Wp^T + b ----------------
// m97 structure: 128x128 tile, BK=64, 4 waves (2x2), global_load_lds w16.
#define GBM 128
#define GBN 128
#define GBK 64

__global__ __launch_bounds__(256) void gemm_bf16(
    const short* __restrict__ Y, const short* __restrict__ Wb,
    const float* __restrict__ bias, float* __restrict__ out) {
  __shared__ __align__(16) short As[GBM * GBK];  // [128][64] row-major, 16 KB
  __shared__ __align__(16) short Bs[GBN * GBK];

  const int tid = threadIdx.x;
  const int lane = tid & 63;
  const int wid = tid >> 6;  // 0..3
  const int wm = wid >> 1, wn = wid & 1;
  const int m0 = blockIdx.y * GBM;
  const int n0 = blockIdx.x * GBN;

  const int srow = lane >> 3;       // 0..7 row within 8-row chunk
  const int scol = (lane & 7) * 8;  // elem col within row

  f32x4 acc[4][4];
#pragma unroll
  for (int m = 0; m < 4; ++m)
#pragma unroll
    for (int n = 0; n < 4; ++n) acc[m][n] = (f32x4){0.f, 0.f, 0.f, 0.f};

  auto stage = [&](int k0) {
#pragma unroll
    for (int c = 0; c < 4; ++c) {
      const int chunk = wid * 4 + c;  // 0..15 (8 rows each)
      const int row = chunk * 8 + srow;
      const short* ga = &Y[(size_t)(m0 + row) * DD + k0 + scol];
      const short* gb = &Wb[(size_t)(n0 + row) * DD + k0 + scol];
      __builtin_amdgcn_global_load_lds(
          (const __attribute__((address_space(1))) unsigned int*)ga,
          (__attribute__((address_space(3))) unsigned int*)((char*)As +
                                                            chunk * 1024),
          16, 0, 0);
      __builtin_amdgcn_global_load_lds(
          (const __attribute__((address_space(1))) unsigned int*)gb,
          (__attribute__((address_space(3))) unsigned int*)((char*)Bs +
                                                            chunk * 1024),
          16, 0, 0);
    }
  };

  const int arow = wm * 64 + (lane & 15);
  const int brow = wn * 64 + (lane & 15);
  const int kfr = (lane >> 4) * 8;

  stage(0);
  const int NK = DD / GBK;  // 8
  for (int k = 0; k < NK; ++k) {
    __syncthreads();  // staging drained, prior compute done
#pragma unroll
    for (int kk = 0; kk < GBK; kk += 32) {
      bf16x8 af[4], bfr[4];
      const int kcol = kk + kfr;
#pragma unroll
      for (int m = 0; m < 4; ++m)
        af[m] = *(const bf16x8*)(const void*)&As[(arow + m * 16) * GBK + kcol];
#pragma unroll
      for (int n = 0; n < 4; ++n)
        bfr[n] = *(const bf16x8*)(const void*)&Bs[(brow + n * 16) * GBK + kcol];
#pragma unroll
      for (int m = 0; m < 4; ++m)
#pragma unroll
        for (int n = 0; n < 4; ++n)
          acc[m][n] = __builtin_amdgcn_mfma_f32_16x16x32_bf16(
              af[m], bfr[n], acc[m][n], 0, 0, 0);
    }
    if (k + 1 < NK) {
      __syncthreads();  // all waves done reading LDS
      stage((k + 1) * GBK);
    }
  }

  // epilogue: D layout col=lane&15, row=(lane>>4)*4+j  [m89 verified]
  const int c16 = lane & 15;
  const int r4 = (lane >> 4) * 4;
#pragma unroll
  for (int m = 0; m < 4; ++m) {
    const int rowb = m0 + wm * 64 + m * 16 + r4;
#pragma unroll
    for (int n = 0; n < 4; ++n) {
      const int col = n0 + wn * 64 + n * 16 + c16;
      const float bv = bias[col];
#pragma unroll
      for (int j = 0; j < 4; ++j)
        out[(size_t)(rowb + j) * DD + col] = acc[m][n][j] + bv;
    }
  }
}

// ---------------- launcher ----------------
extern "C" void kernel_launch(void* const* d_in, const int* in_sizes, int n_in,
                              void* d_out, int out_size, void* d_ws,
                              size_t ws_size, hipStream_t stream) {
  const float* x = (const float*)d_in[0];
  const float* A = (const float*)d_in[3];
  const float* Bm = (const float*)d_in[4];
  const float* Cm = (const float*)d_in[5];
  const float* Dsk = (const float*)d_in[6];
  const float* Wp = (const float*)d_in[7];
  const float* bpj = (const float*)d_in[8];
  float* out = (float*)d_out;

  short* yws = (short*)d_ws;                                   // 16 MB bf16 y
  short* wb = (short*)((char*)d_ws + (size_t)MROWS * DD * 2);  // 512 KB bf16 Wp

  // scan_h + fused Wp conversion (blocks x >= 256)
  const dim3 grid_h(256 + 64, DD / 256);
  scan_kernel<true><<<grid_h, 256, 0, stream>>>(x, A, Bm, Cm, Dsk, yws, Wp, wb);
  const dim3 grid_v(256, DD / 256);
  scan_kernel<false><<<grid_v, 256, 0, stream>>>(x, A, Bm, Cm, Dsk, yws, Wp,
                                                 wb);

  const dim3 gemm_grid(DD / GBN, MROWS / GBM);  // (4, 128)
  gemm_bf16<<<gemm_grid, 256, 0, stream>>>(yws, wb, bpj, out);
}

// Round 4
// 42.345 us; speedup vs baseline: 3.7600x; 1.1385x over previous
//
#include <hip/hip_runtime.h>

// DirectionalScan: B=4, H=64, W=64, D=512, N=8
// out = ((scan_h(x) + scan_v(x)) @ Wp^T) + b_proj
#define BB 4
#define HH 64
#define WW 64
#define DD 512
#define NS 8
#define MROWS (BB * HH * WW)  // 16384

typedef __attribute__((ext_vector_type(8))) __bf16 bf16x8;
typedef __attribute__((ext_vector_type(4))) float f32x4;

__device__ inline short f2bf(float f) {  // RNE f32 -> bf16 bits
  unsigned u = __float_as_uint(f);
  return (short)((u + 0x7fff + ((u >> 16) & 1)) >> 16);
}
__device__ inline float bf2f(short s) {
  return __uint_as_float(((unsigned)(unsigned short)s) << 16);
}

// ---------------- kernel 1: scan_h (writes y_h bf16) + fused Wp->bf16 -------
__global__ __launch_bounds__(256) void scan_h_kernel(
    const float* __restrict__ x, const float* __restrict__ A,
    const float* __restrict__ Bm, const float* __restrict__ Cm,
    const float* __restrict__ Dsk, short* __restrict__ y,
    const float* __restrict__ Wp, short* __restrict__ wb) {
  if (blockIdx.x >= 256) {
    // fused Wp f32->bf16 conversion: 128 conv blocks x 256 thr x 8 elems
    const int cid = (blockIdx.x - 256) * 2 + blockIdx.y;  // 0..127
    const int i = (cid * 256 + (int)threadIdx.x) * 8;
    const float4 v0 = *(const float4*)&Wp[i];
    const float4 v1 = *(const float4*)&Wp[i + 4];
    short r[8];
    r[0] = f2bf(v0.x); r[1] = f2bf(v0.y); r[2] = f2bf(v0.z); r[3] = f2bf(v0.w);
    r[4] = f2bf(v1.x); r[5] = f2bf(v1.y); r[6] = f2bf(v1.z); r[7] = f2bf(v1.w);
    *(short4*)&wb[i] = *(short4*)&r[0];
    *(short4*)&wb[i + 4] = *(short4*)&r[4];
    return;
  }

  const int seq = blockIdx.x;  // 0..255 = b*64 + w
  const int d = blockIdx.y * 256 + threadIdx.x;
  const int b = seq >> 6;
  const int r = seq & 63;

  size_t base = ((size_t)b * HH * WW + r) * DD + d;
  const size_t step = (size_t)WW * DD;

  float a[NS], bm[NS], cm[NS], s[NS];
#pragma unroll
  for (int i = 0; i < NS; i += 4) {
    float4 t;
    t = *(const float4*)&A[(size_t)d * NS + i];
    a[i] = t.x; a[i + 1] = t.y; a[i + 2] = t.z; a[i + 3] = t.w;
    t = *(const float4*)&Bm[(size_t)d * NS + i];
    bm[i] = t.x; bm[i + 1] = t.y; bm[i + 2] = t.z; bm[i + 3] = t.w;
    t = *(const float4*)&Cm[(size_t)d * NS + i];
    cm[i] = t.x; cm[i + 1] = t.y; cm[i + 2] = t.z; cm[i + 3] = t.w;
  }
  const float dk = Dsk[d];
#pragma unroll
  for (int i = 0; i < NS; ++i) s[i] = 0.f;

  float xs[2][8];
#pragma unroll
  for (int i = 0; i < 8; ++i) xs[0][i] = x[base + (size_t)i * step];

#pragma unroll 2
  for (int c = 0; c < 8; ++c) {
    const int cur = c & 1, nxt = cur ^ 1;
    const size_t nbase = base + 8 * step;
    if (c < 7) {
#pragma unroll
      for (int i = 0; i < 8; ++i) xs[nxt][i] = x[nbase + (size_t)i * step];
    }
#pragma unroll
    for (int i = 0; i < 8; ++i) {
      const float xv = xs[cur][i];
      float acc = dk * xv;
#pragma unroll
      for (int n = 0; n < NS; ++n) {
        s[n] = fmaf(a[n], s[n], bm[n] * xv);
        acc = fmaf(s[n], cm[n], acc);
      }
      y[base + (size_t)i * step] = f2bf(acc);
    }
    base = nbase;
  }
}

// ------- kernel 2: fused scan_v + y_h add + GEMM(Y @ Wp^T) + bias ----------
// One block per (b,h): 64 contiguous output rows. 512 threads = 8 waves.
// Phase 1: thread d scans w=0..63, writes bf16 Y-tile into swizzled LDS.
// Phase 2: 64x512x512 GEMM from LDS; B (Wp) staged per-K-step, source-swizzled.
__global__ __launch_bounds__(512) void scanv_gemm_kernel(
    const float* __restrict__ x, const float* __restrict__ A,
    const float* __restrict__ Bm, const float* __restrict__ Cm,
    const float* __restrict__ Dsk, const short* __restrict__ yh,
    const short* __restrict__ Wb, const float* __restrict__ bias,
    float* __restrict__ out) {
  __shared__ __align__(16) short Ys[64 * DD];  // 64 KB  [w][d^((w&7)<<3)]
  __shared__ __align__(16) short Bs[DD * 64];  // 64 KB  [n][k^((n&7)<<3)]

  const int tid = (int)threadIdx.x;  // 0..511
  const int lane = tid & 63;
  const int wid = tid >> 6;  // 0..7
  const int m0 = blockIdx.x * 64;
  const int d = tid;

  // stage Bs K-slab k0 (LDS linear dest, inverse-swizzled global source)
  auto stageB = [&](int k0) {
#pragma unroll
    for (int i = 0; i < 8; ++i) {
      const int n = i * 64 + wid * 8 + (lane >> 3);          // Wp row 0..511
      const int ksw = ((lane & 7) ^ (n & 7)) << 3;           // swizzled k-slot
      const short* g = &Wb[(size_t)n * DD + k0 + ksw];
      __builtin_amdgcn_global_load_lds(
          (const __attribute__((address_space(1))) unsigned int*)g,
          (__attribute__((address_space(3))) unsigned int*)((char*)Bs +
                                                            i * 8192 +
                                                            wid * 1024),
          16, 0, 0);
    }
  };

  // ---- phase 1: scan over w (issue first x/yh chunk, then Bs(0)) ----
  float a[NS], bm[NS], cm[NS], s[NS];
#pragma unroll
  for (int i = 0; i < NS; i += 4) {
    float4 t;
    t = *(const float4*)&A[(size_t)d * NS + i];
    a[i] = t.x; a[i + 1] = t.y; a[i + 2] = t.z; a[i + 3] = t.w;
    t = *(const float4*)&Bm[(size_t)d * NS + i];
    bm[i] = t.x; bm[i + 1] = t.y; bm[i + 2] = t.z; bm[i + 3] = t.w;
    t = *(const float4*)&Cm[(size_t)d * NS + i];
    cm[i] = t.x; cm[i + 1] = t.y; cm[i + 2] = t.z; cm[i + 3] = t.w;
  }
  const float dk = Dsk[d];
#pragma unroll
  for (int i = 0; i < NS; ++i) s[i] = 0.f;

  size_t base = (size_t)m0 * DD + d;
  float xs[2][8], yp[2][8];
#pragma unroll
  for (int i = 0; i < 8; ++i) xs[0][i] = x[base + (size_t)i * DD];
#pragma unroll
  for (int i = 0; i < 8; ++i) yp[0][i] = bf2f(yh[base + (size_t)i * DD]);

  stageB(0);  // hides under the scan; drained by the barrier below

#pragma unroll 2
  for (int c = 0; c < 8; ++c) {
    const int cur = c & 1, nxt = cur ^ 1;
    const size_t nbase = base + 8 * DD;
    if (c < 7) {
#pragma unroll
      for (int i = 0; i < 8; ++i) xs[nxt][i] = x[nbase + (size_t)i * DD];
#pragma unroll
      for (int i = 0; i < 8; ++i)
        yp[nxt][i] = bf2f(yh[nbase + (size_t)i * DD]);
    }
#pragma unroll
    for (int i = 0; i < 8; ++i) {
      const int w = c * 8 + i;
      const float xv = xs[cur][i];
      float acc = fmaf(dk, xv, yp[cur][i]);
#pragma unroll
      for (int n = 0; n < NS; ++n) {
        s[n] = fmaf(a[n], s[n], bm[n] * xv);
        acc = fmaf(s[n], cm[n], acc);
      }
      Ys[w * DD + (d ^ ((w & 7) << 3))] = f2bf(acc);
    }
    base = nbase;
  }

  __syncthreads();  // Ys complete; Bs(0) drained (vmcnt0 before barrier)

  // ---- phase 2: out[m0+0..63][0..511] = Ys @ Wb^T + bias ----
  f32x4 acc[4][4];
#pragma unroll
  for (int m = 0; m < 4; ++m)
#pragma unroll
    for (int n = 0; n < 4; ++n) acc[m][n] = (f32x4){0.f, 0.f, 0.f, 0.f};

  const int fr = lane & 15;        // fragment row
  const int kfr = (lane >> 4) * 8; // k sub-slice

  for (int k = 0; k < DD / 64; ++k) {  // 8 K-steps of 64
    const int k0 = k * 64;
#pragma unroll
    for (int kk = 0; kk < 64; kk += 32) {
      bf16x8 af[4], bfv[4];
#pragma unroll
      for (int m = 0; m < 4; ++m) {
        const int r = m * 16 + fr;                 // Y row 0..63
        const int cc = k0 + kk + kfr;              // global k col
        af[m] = *(const bf16x8*)(const void*)&Ys[r * DD +
                                                 (cc ^ ((r & 7) << 3))];
      }
#pragma unroll
      for (int n = 0; n < 4; ++n) {
        const int nn = wid * 64 + n * 16 + fr;     // Wp row (out col) 0..511
        const int cl = kk + kfr;                   // local k col 0..63
        bfv[n] = *(const bf16x8*)(const void*)&Bs[nn * 64 +
                                                  (cl ^ ((nn & 7) << 3))];
      }
#pragma unroll
      for (int m = 0; m < 4; ++m)
#pragma unroll
        for (int n = 0; n < 4; ++n)
          acc[m][n] = __builtin_amdgcn_mfma_f32_16x16x32_bf16(
              af[m], bfv[n], acc[m][n], 0, 0, 0);
    }
    if (k + 1 < DD / 64) {
      __syncthreads();           // all waves done reading Bs
      stageB((k + 1) * 64);
      __syncthreads();           // staged (vmcnt drained before barrier)
    }
  }

  // epilogue: D layout col=lane&15, row=(lane>>4)*4+j  [m89 verified]
  const int c16 = lane & 15;
  const int r4 = (lane >> 4) * 4;
#pragma unroll
  for (int m = 0; m < 4; ++m) {
    const int rowb = m0 + m * 16 + r4;
#pragma unroll
    for (int n = 0; n < 4; ++n) {
      const int col = wid * 64 + n * 16 + c16;
      const float bv = bias[col];
#pragma unroll
      for (int j = 0; j < 4; ++j)
        out[(size_t)(rowb + j) * DD + col] = acc[m][n][j] + bv;
    }
  }
}

// ---------------- launcher ----------------
extern "C" void kernel_launch(void* const* d_in, const int* in_sizes, int n_in,
                              void* d_out, int out_size, void* d_ws,
                              size_t ws_size, hipStream_t stream) {
  const float* x = (const float*)d_in[0];
  const float* A = (const float*)d_in[3];
  const float* Bm = (const float*)d_in[4];
  const float* Cm = (const float*)d_in[5];
  const float* Dsk = (const float*)d_in[6];
  const float* Wp = (const float*)d_in[7];
  const float* bpj = (const float*)d_in[8];
  float* out = (float*)d_out;

  short* yws = (short*)d_ws;                                   // 16 MB bf16 y_h
  short* wb = (short*)((char*)d_ws + (size_t)MROWS * DD * 2);  // 512 KB bf16 Wp

  // scan_h + fused Wp conversion (blocks x >= 256)
  const dim3 grid_h(256 + 64, DD / 256);
  scan_h_kernel<<<grid_h, 256, 0, stream>>>(x, A, Bm, Cm, Dsk, yws, Wp, wb);

  // fused scan_v + add + projection
  scanv_gemm_kernel<<<BB * HH, 512, 0, stream>>>(x, A, Bm, Cm, Dsk, yws, wb,
                                                 bpj, out);
}